// Round 15
// baseline (1177.130 us; speedup 1.0000x reference)
//
#include <hip/hip_runtime.h>
#include <math.h>

// Fused separable-Gaussian SSIM. N=32,C=3,H=W=512 fp32.
// Windows (5,11),(11,5),(11,11), sigma=1.5, zero padding.
// u/v reformulation (u=x+y, v=x-y) + packed fp32 (v_pk_fma_f32 via v2).
// LDS layout = R11 (dense, NO swizzle — R12's chunk-XOR swizzle measured
// WORSE: conflicts 11.0M->18.9M, dur +9us; reverted).
// NEW vs R11: global loads for iteration i+1 are prefetched into a ping-pong
// register buffer right after iter i's V-write barrier, so their ~900-cycle
// HBM latency hides under iter i's H phase instead of stalling every wave at
// the top of V. Main loop unrolled x2 so buffer selection is compile-time.
//   A(5,11)=H11(inner)  B(11,5)=H5(full)  C(11,11)=H11(full)

#define H 512
#define W 512
#define NPLANE 96
#define TW 128          // output cols per block
#define PW 138          // TW + 10 halo cols
#define PWP 140         // padded LDS row of v2 (1120B, 16B-aligned)
#define BAND 128        // output rows per block
#define R 8             // rows per barrier iteration
#define NITER (BAND / R)
#define NTHREADS 256    // 4 waves; H phase has exactly 256 slots

typedef float v2 __attribute__((ext_vector_type(2)));

struct GaussW {
  float e[11];                  // raw exp(-d^2/4.5) weights
  float k2A, k1A, k2C, k1C;     // .5*s, .5*s^2 for combos A/B and C
};

// m = raw (mu_u, mu_v), s = raw (Muu, Mvv); k2=.5*scale, k1=.5*scale^2
__device__ __forceinline__ float ssim_uv(v2 m, v2 s, float k2, float k1) {
  const float C1 = 0.0001f;   // 0.01^2
  const float C2 = 0.0009f;   // 0.03^2
  v2 PQ = m * m;                       // v_pk_mul_f32
  float t1 = PQ.x - PQ.y, t2 = PQ.x + PQ.y;
  float n1 = fmaf(k1, t1, C1);
  float d1 = fmaf(k1, t2, C1);
  float u1 = s.x - s.y, u2 = s.x + s.y;
  float n2 = fmaf(k2, u1, fmaf(-k1, t1, C2));
  float d2 = fmaf(k2, u2, fmaf(-k1, t2, C2));
  return (n1 * n2) * __builtin_amdgcn_rcpf(d1 * d2);  // den >= C1*C2 > 0
}

__device__ __forceinline__ void issue_loads(const float* __restrict__ p1,
                                            const float* __restrict__ p2,
                                            int rbase, bool colok, int col,
                                            float (&nx)[R], float (&ny)[R]) {
#pragma unroll
  for (int sub = 0; sub < R; ++sub) {
    const int rr = rbase + sub + 5;
    bool ok = colok && (rr < H);
    nx[sub] = ok ? p1[rr * W + col] : 0.0f;
    ny[sub] = ok ? p2[rr * W + col] : 0.0f;
  }
}

__device__ __forceinline__ void v_phase(const GaussW& w, int t,
                                        v2 (*sV)[4][PWP],
                                        v2 (&wUV)[11], v2 (&wQ)[11],
                                        const float (&nx)[R],
                                        const float (&ny)[R]) {
#pragma unroll
  for (int sub = 0; sub < R; ++sub) {
    v2 uv; uv.x = nx[sub] + ny[sub]; uv.y = nx[sub] - ny[sub];
    wUV[10] = uv; wQ[10] = uv * uv;
    v2 iUV = {0, 0}, iQ = {0, 0}, oUV = {0, 0}, oQ = {0, 0};
#pragma unroll
    for (int k = 0; k < 11; ++k) {
      v2 ek = {w.e[k], w.e[k]};
      if (k >= 3 && k <= 7) {
        iUV = __builtin_elementwise_fma(ek, wUV[k], iUV);
        iQ  = __builtin_elementwise_fma(ek, wQ[k], iQ);
      } else {
        oUV = __builtin_elementwise_fma(ek, wUV[k], oUV);
        oQ  = __builtin_elementwise_fma(ek, wQ[k], oQ);
      }
    }
    sV[sub][0][t] = iUV;
    sV[sub][1][t] = iQ;
    sV[sub][2][t] = iUV + oUV;
    sV[sub][3][t] = iQ + oQ;
#pragma unroll
    for (int k = 0; k < 10; ++k) {               // shift (renamed by unroll)
      wUV[k] = wUV[k + 1]; wQ[k] = wQ[k + 1];
    }
  }
}

__device__ __forceinline__ float h_phase(const GaussW& w, int t,
                                         v2 (*sV)[4][PWP]) {
  const int sub = t >> 5;
  const int cb = (t & 31) * 4;       // first of 4 output cols (16B aligned)
  float iterSum = 0.0f;

  v2 fUV[14], fQ[14];
  // Combo A: 11-tap conv over inner pair-channels, SSIM with A constants
  {
#pragma unroll
    for (int pc = 0; pc < 2; ++pc) {
      const float4* vp = (const float4*)&sV[sub][pc][cb];
      v2* dst = pc ? fQ : fUV;
#pragma unroll
      for (int q = 0; q < 7; ++q) {
        float4 r4 = vp[q];
        v2 lo; lo.x = r4.x; lo.y = r4.y;
        v2 hi; hi.x = r4.z; hi.y = r4.w;
        dst[2 * q] = lo; dst[2 * q + 1] = hi;
      }
    }
#pragma unroll
    for (int k = 0; k < 4; ++k) {
      v2 aUV = {0, 0}, aQ = {0, 0};
#pragma unroll
      for (int j = 0; j < 11; ++j) {
        v2 ej = {w.e[j], w.e[j]};
        aUV = __builtin_elementwise_fma(ej, fUV[k + j], aUV);
        aQ  = __builtin_elementwise_fma(ej, fQ[k + j], aQ);
      }
      iterSum += ssim_uv(aUV, aQ, w.k2A, w.k1A);
    }
  }
  // Combos C (full 11) and B (inner 5) share inner/outer over full channels
  {
#pragma unroll
    for (int pc = 0; pc < 2; ++pc) {
      const float4* vp = (const float4*)&sV[sub][2 + pc][cb];
      v2* dst = pc ? fQ : fUV;
#pragma unroll
      for (int q = 0; q < 7; ++q) {
        float4 r4 = vp[q];
        v2 lo; lo.x = r4.x; lo.y = r4.y;
        v2 hi; hi.x = r4.z; hi.y = r4.w;
        dst[2 * q] = lo; dst[2 * q + 1] = hi;
      }
    }
#pragma unroll
    for (int k = 0; k < 4; ++k) {
      v2 biUV = {0, 0}, biQ = {0, 0}, boUV = {0, 0}, boQ = {0, 0};
#pragma unroll
      for (int j = 0; j < 11; ++j) {
        v2 ej = {w.e[j], w.e[j]};
        if (j >= 3 && j <= 7) {
          biUV = __builtin_elementwise_fma(ej, fUV[k + j], biUV);
          biQ  = __builtin_elementwise_fma(ej, fQ[k + j], biQ);
        } else {
          boUV = __builtin_elementwise_fma(ej, fUV[k + j], boUV);
          boQ  = __builtin_elementwise_fma(ej, fQ[k + j], boQ);
        }
      }
      iterSum += ssim_uv(biUV + boUV, biQ + boQ, w.k2C, w.k1C);
      iterSum += ssim_uv(biUV, biQ, w.k2A, w.k1A);
    }
  }
  return iterSum;
}

__global__ __launch_bounds__(NTHREADS, 4) void ssim_kernel(
    const float* __restrict__ img1, const float* __restrict__ img2,
    double* __restrict__ acc, GaussW w) {
  // pair-channels: 0 = inner(u,v), 1 = inner(uu,vv), 2 = full(u,v), 3 = full(uu,vv)
  __shared__ __align__(16) v2 sV[R][4][PWP];      // 35.8 KB -> 4 blocks/CU
  __shared__ double red[NTHREADS / 64];

  const int t = threadIdx.x;
  const int tile = blockIdx.x, band = blockIdx.y, plane = blockIdx.z;
  const float* p1 = img1 + (size_t)plane * H * W;
  const float* p2 = img2 + (size_t)plane * H * W;
  const int c0 = tile * TW;
  const int r0 = band * BAND;
  const int col = c0 + t - 5;            // column owned in V phase
  const bool vact = (t < PW);
  const bool colok = vact && ((unsigned)col < (unsigned)W);

  // rolling windows: slot k = row (r-5+k) for current output row r
  v2 wUV[11], wQ[11];
#pragma unroll
  for (int k = 0; k < 10; ++k) {
    int rr = r0 - 5 + k;
    bool ok = colok && (rr >= 0);
    float x = ok ? p1[rr * W + col] : 0.0f;
    float y = ok ? p2[rr * W + col] : 0.0f;
    v2 uv; uv.x = x + y; uv.y = x - y;
    wUV[k] = uv; wQ[k] = uv * uv;
  }

  // ping-pong prefetch buffers (explicit A/B, loop unrolled x2 -> static use)
  float nxA[R], nyA[R], nxB[R], nyB[R];
  issue_loads(p1, p2, r0, colok, col, nxA, nyA);       // rows for iter 0

  double accT = 0.0;
  for (int it = 0; it < NITER; it += 2) {
    // ---- iteration it (even): consume A
    if (vact) v_phase(w, t, sV, wUV, wQ, nxA, nyA);
    __syncthreads();
    issue_loads(p1, p2, r0 + (it + 1) * R, colok, col, nxB, nyB);  // prefetch
    accT += (double)h_phase(w, t, sV);
    __syncthreads();

    // ---- iteration it+1 (odd): consume B
    if (vact) v_phase(w, t, sV, wUV, wQ, nxB, nyB);
    __syncthreads();
    if (it + 2 < NITER)
      issue_loads(p1, p2, r0 + (it + 2) * R, colok, col, nxA, nyA);
    accT += (double)h_phase(w, t, sV);
    __syncthreads();
  }

  // block reduction (4 waves) -> one device atomic per block
#pragma unroll
  for (int off = 32; off > 0; off >>= 1) accT += __shfl_down(accT, off);
  const int wid = t >> 6;
  if ((t & 63) == 0) red[wid] = accT;
  __syncthreads();
  if (t == 0) {
    double s = 0.0;
    for (int k = 0; k < NTHREADS / 64; ++k) s += red[k];
    atomicAdd(acc, s);
  }
}

__global__ void finalize_kernel(const double* __restrict__ acc,
                                float* __restrict__ out) {
  out[0] = (float)(acc[0] * (1.0 / (3.0 * (double)NPLANE * H * W)));
}

extern "C" void kernel_launch(void* const* d_in, const int* in_sizes, int n_in,
                              void* d_out, int out_size, void* d_ws,
                              size_t ws_size, hipStream_t stream) {
  const float* img1 = (const float*)d_in[0];
  const float* img2 = (const float*)d_in[1];
  float* out = (float*)d_out;
  double* acc = (double*)d_ws;

  hipMemsetAsync(acc, 0, sizeof(double), stream);

  GaussW w;
  {
    double e64[11], S11 = 0.0, S5 = 0.0;
    for (int i = 0; i < 11; ++i) {
      double d = (double)(i - 5);
      e64[i] = exp(-d * d / 4.5);   // 2*sigma^2 = 4.5
      S11 += e64[i];
      if (i >= 3 && i <= 7) S5 += e64[i];
    }
    for (int i = 0; i < 11; ++i) w.e[i] = (float)e64[i];
    double sA = 1.0 / (S5 * S11);    // combos A and B
    double sC = 1.0 / (S11 * S11);   // combo C
    w.k2A = (float)(0.5 * sA);
    w.k1A = (float)(0.5 * sA * sA);
    w.k2C = (float)(0.5 * sC);
    w.k1C = (float)(0.5 * sC * sC);
  }

  dim3 grid(W / TW, H / BAND, NPLANE);   // 4 x 4 x 96 = 1536 blocks (4/CU)
  ssim_kernel<<<grid, NTHREADS, 0, stream>>>(img1, img2, acc, w);
  finalize_kernel<<<1, 1, 0, stream>>>(acc, out);
}